// Round 17
// baseline (2054.112 us; speedup 1.0000x reference)
//
#include <hip/hip_runtime.h>
#include <hip/hip_bf16.h>
#include <math.h>

#define BB 64
#define HW 196
#define FEAT 2048
#define EMB 512
#define HID 1024
#define ATT 512
#define VOCAB 10000
#define TT 20
#define STEPS 19

using bfrag = __attribute__((ext_vector_type(8))) short;   // 8 bf16 = 4 VGPR
using f32x4 = __attribute__((ext_vector_type(4))) float;

__device__ __forceinline__ float sigmoid_fast(float x) { return 1.0f / (1.0f + __expf(-x)); }
__device__ __forceinline__ float tanh_fast(float x) {
    float e = __expf(2.0f * x);
    return 1.0f - 2.0f / (e + 1.0f);
}
__device__ __forceinline__ ushort f2bf_rne(float f) {
    unsigned u = __float_as_uint(f);
    unsigned r = (u + 0x7FFFu + ((u >> 16) & 1u)) >> 16;
    return (ushort)r;
}
__device__ __forceinline__ float bf2f(ushort h) {
    return __uint_as_float(((unsigned)h) << 16);
}
// XOR bank swizzle for 16B LDS chunks (R10-verified conflict-free).
__device__ __forceinline__ int sw_idx(int row, int g) { return row * 4 + (g ^ ((row >> 1) & 3)); }

// ---------------------------------------------------------------------------
__global__ __launch_bounds__(256) void k_split(const float* __restrict__ x,
                                               ushort* __restrict__ hi,
                                               ushort* __restrict__ lo, int n)
{
    int i4 = (blockIdx.x * 256 + threadIdx.x) * 4;
    if (i4 >= n) return;
    float4 v = *(const float4*)(x + i4);
    float av[4] = {v.x, v.y, v.z, v.w};
    #pragma unroll
    for (int j = 0; j < 4; ++j) {
        ushort h = f2bf_rne(av[j]);
        hi[i4 + j] = h;
        lo[i4 + j] = f2bf_rne(av[j] - bf2f(h));
    }
}

__global__ __launch_bounds__(256) void k_cvt(const float* __restrict__ x,
                                             ushort* __restrict__ y, int n)
{
    int i4 = (blockIdx.x * 256 + threadIdx.x) * 4;
    if (i4 >= n) return;
    float4 v = *(const float4*)(x + i4);
    *(ushort4*)(y + i4) = make_ushort4(f2bf_rne(v.x), f2bf_rne(v.y),
                                       f2bf_rne(v.z), f2bf_rne(v.w));
}

// ---------------------------------------------------------------------------
// mfma_g (R15/R16-verified).
// ---------------------------------------------------------------------------
template<bool NFAST, bool GLDS>
__global__ __launch_bounds__(256) void mfma_g(
    const float* __restrict__ A,
    const ushort* __restrict__ Bhi, const ushort* __restrict__ Blo,
    const float* __restrict__ bias, float* __restrict__ C,
    int N, int K, int Bld, int ldc, int NXB, int NMB)
{
    __shared__ __align__(16) ushort sAh[256 * 8];
    __shared__ __align__(16) ushort sAl[256 * 8];
    __shared__ __align__(16) ushort sBh[512 * 8];
    __shared__ __align__(16) ushort sBl[512 * 8];

    const int tid = threadIdx.x;

    const int nwg = NXB * NMB;
    const int q = nwg >> 3, r = nwg & 7;
    const int xcd = blockIdx.x & 7, sidx = blockIdx.x >> 3;
    const int wg = (xcd < r) ? (xcd * (q + 1) + sidx)
                             : (r * (q + 1) + (xcd - r) * q + sidx);
    int im, inb;
    if (NFAST) { inb = wg % NXB; im = wg / NXB; }
    else       { im = wg % NMB; inb = wg / NMB; }
    const int m0 = im * 64;
    const int n0 = inb * 128;

    const int lane = tid & 63;
    const int w = tid >> 6;
    const int mh = (w & 1) * 32;
    const int nh = (w >> 1) * 64;
    const int g = lane >> 4, l15 = lane & 15;

    const ushort* bsrc[4];
    ushort* bdst[4];
    if (GLDS) {
        #pragma unroll
        for (int i = 0; i < 4; ++i) {
            int cbase = i * 256 + w * 64;
            int plane = cbase >> 9;
            int ccb = cbase & 511;
            int cc = ccb + lane;
            int row = cc >> 2;
            int g_ = (cc & 3) ^ ((row >> 1) & 3);
            int brow = min(n0 + row, N - 1);
            bsrc[i] = (plane ? Blo : Bhi) + (size_t)brow * Bld + g_ * 8;
            bdst[i] = (plane ? sBl : sBh) + ccb * 8;
        }
    }

    f32x4 acc[2][4] = {};

    for (int k0 = 0; k0 < K; k0 += 32) {
        __syncthreads();
        {
            int r_ = tid >> 2, g_ = tid & 3;
            const float* ap = A + (size_t)(m0 + r_) * K + k0 + g_ * 8;
            float av[8];
            *(float4*)(av)     = *(const float4*)(ap);
            *(float4*)(av + 4) = *(const float4*)(ap + 4);
            bfrag vh, vl;
            #pragma unroll
            for (int j = 0; j < 8; ++j) {
                ushort h = f2bf_rne(av[j]);
                vh[j] = (short)h;
                vl[j] = (short)f2bf_rne(av[j] - bf2f(h));
            }
            int c = sw_idx(r_, g_) * 8;
            *(bfrag*)&sAh[c] = vh;
            *(bfrag*)&sAl[c] = vl;
        }
        if (GLDS) {
            #pragma unroll
            for (int i = 0; i < 4; ++i)
                __builtin_amdgcn_global_load_lds(
                    (const __attribute__((address_space(1))) void*)(bsrc[i] + k0),
                    (__attribute__((address_space(3))) void*)bdst[i], 16, 0, 0);
        } else {
            #pragma unroll
            for (int i = 0; i < 4; ++i) {
                int c = tid + i * 256;
                int pl = c >> 9, idx2 = c & 511;
                int r_ = idx2 >> 2, g_ = idx2 & 3;
                int brow = min(n0 + r_, N - 1);
                const ushort* src = (pl ? Blo : Bhi) + (size_t)brow * Bld + k0 + g_ * 8;
                int cc = sw_idx(r_, g_) * 8;
                if (pl) *(bfrag*)&sBl[cc] = *(const bfrag*)src;
                else    *(bfrag*)&sBh[cc] = *(const bfrag*)src;
            }
        }
        __syncthreads();

        bfrag ah[2], al[2], bh[4], bl[4];
        #pragma unroll
        for (int s = 0; s < 2; ++s) {
            int c = sw_idx(mh + s * 16 + l15, g) * 8;
            ah[s] = *(const bfrag*)&sAh[c];
            al[s] = *(const bfrag*)&sAl[c];
        }
        #pragma unroll
        for (int u = 0; u < 4; ++u) {
            int c = sw_idx(nh + u * 16 + l15, g) * 8;
            bh[u] = *(const bfrag*)&sBh[c];
            bl[u] = *(const bfrag*)&sBl[c];
        }
        #pragma unroll
        for (int s = 0; s < 2; ++s)
            #pragma unroll
            for (int u = 0; u < 4; ++u) {
                acc[s][u] = __builtin_amdgcn_mfma_f32_16x16x32_bf16(ah[s], bh[u], acc[s][u], 0, 0, 0);
                acc[s][u] = __builtin_amdgcn_mfma_f32_16x16x32_bf16(ah[s], bl[u], acc[s][u], 0, 0, 0);
                acc[s][u] = __builtin_amdgcn_mfma_f32_16x16x32_bf16(al[s], bh[u], acc[s][u], 0, 0, 0);
            }
    }

    #pragma unroll
    for (int s = 0; s < 2; ++s)
        #pragma unroll
        for (int u = 0; u < 4; ++u) {
            int col = n0 + nh + u * 16 + l15;
            if (col < N) {
                float bv = bias ? bias[col] : 0.f;
                #pragma unroll
                for (int rr = 0; rr < 4; ++rr) {
                    int row = m0 + mh + s * 16 + g * 4 + rr;
                    C[(size_t)row * ldc + col] = acc[s][u][rr] + bv;
                }
            }
        }
}

// ---------------------------------------------------------------------------
__global__ __launch_bounds__(256) void k_fmean2(const float* __restrict__ f,
                                                float* __restrict__ fmean)
{
    __shared__ float part[128];
    int blk = blockIdx.x;
    int b = blk >> 2, eq = blk & 3;
    int el = threadIdx.x & 127, half = threadIdx.x >> 7;
    int e = eq * 128 + el;
    const float* fb = f + (size_t)b * HW * EMB + e;
    float s = 0.f;
    int h0 = half * 98;
    for (int h = h0; h < h0 + 98; ++h) s += fb[(size_t)h * EMB];
    if (half) part[el] = s;
    __syncthreads();
    if (!half) fmean[b * EMB + e] = (s + part[el]) * (1.0f / HW);
}

__global__ __launch_bounds__(256) void k_init2(
    const float* __restrict__ fmean,
    const float* __restrict__ W_hi, const float* __restrict__ b_hi,
    const float* __restrict__ W_ci, const float* __restrict__ b_ci,
    float* __restrict__ hx, float* __restrict__ cx,
    ushort* __restrict__ hxp_h, ushort* __restrict__ hxp_l)
{
    int o = blockIdx.x * 256 + threadIdx.x;
    int b = o >> 11, uu = o & 2047;
    bool isC = uu >= 1024;
    int u = uu & 1023;
    const float4* wr = (const float4*)((isC ? W_ci : W_hi) + (size_t)u * EMB);
    const float4* fm = (const float4*)(fmean + (size_t)b * EMB);
    float s = isC ? b_ci[u] : b_hi[u];
    #pragma unroll 8
    for (int k = 0; k < EMB / 4; ++k) {
        float4 wv = wr[k], xv = fm[k];
        s += wv.x*xv.x + wv.y*xv.y + wv.z*xv.z + wv.w*xv.w;
    }
    int idx = b * HID + u;
    if (isC) cx[idx] = s;
    else {
        hx[idx] = s;
        ushort hh = f2bf_rne(s);
        hxp_h[idx] = hh;
        hxp_l[idx] = f2bf_rne(s - bf2f(hh));
    }
}

__global__ __launch_bounds__(128) void k_embed(const int* __restrict__ cap,
                                               const float* __restrict__ E,
                                               float* __restrict__ xs_f)
{
    int blk = blockIdx.x;
    int t = blk / BB, b = blk % BB;
    int c = cap[b * TT + t];
    const float4* src = (const float4*)(E + (size_t)c * EMB);
    float4* dst = (float4*)(xs_f + ((size_t)t * BB + b) * EMB);
    dst[threadIdx.x] = src[threadIdx.x];
}

__global__ void k_bar_init(int* bar) { bar[threadIdx.x] = 0; }

// ---------------------------------------------------------------------------
// Hierarchical grid barrier, RELAXED polls (no per-poll L2 invalidate --
// R5's failure mode), single acquire fence at exit. 16 groups x 16 blocks.
// ---------------------------------------------------------------------------
__device__ __forceinline__ void gbar(int* bar) {
    __syncthreads();
    if (threadIdx.x == 0) {
        __threadfence();                               // release (agent)
        int* gen  = bar;
        int* rcnt = bar + 32;
        int* gcnt = bar + 64 + (blockIdx.x & 15) * 32;
        int g = __hip_atomic_load(gen, __ATOMIC_RELAXED, __HIP_MEMORY_SCOPE_AGENT);
        bool done = false;
        if (__hip_atomic_fetch_add(gcnt, 1, __ATOMIC_RELAXED, __HIP_MEMORY_SCOPE_AGENT) == 15) {
            __hip_atomic_store(gcnt, 0, __ATOMIC_RELAXED, __HIP_MEMORY_SCOPE_AGENT);
            if (__hip_atomic_fetch_add(rcnt, 1, __ATOMIC_RELAXED, __HIP_MEMORY_SCOPE_AGENT) == 15) {
                __hip_atomic_store(rcnt, 0, __ATOMIC_RELAXED, __HIP_MEMORY_SCOPE_AGENT);
                __hip_atomic_fetch_add(gen, 1, __ATOMIC_RELEASE, __HIP_MEMORY_SCOPE_AGENT);
                done = true;
            }
        }
        if (!done)
            while (__hip_atomic_load(gen, __ATOMIC_RELAXED, __HIP_MEMORY_SCOPE_AGENT) == g)
                __builtin_amdgcn_s_sleep(1);
        __builtin_amdgcn_fence(__ATOMIC_ACQUIRE, "agent");   // one invalidate
    }
    __syncthreads();
}

// ---------------------------------------------------------------------------
// k_steps: persistent step loop. 256 blocks x 512 threads (1 block/CU,
// co-resident by construction). 4 phases/step, bodies taken from the
// R12/R16-verified kernels:
//   A: ha (256 blk: 16a x 8b x 4 K-quarters)        -> bar
//   B1: logits (256 blk: b x 4 h-quarters, fa16)    -> bar
//   B2: softmax + ctx (256 blk: b x 4 e-quarters)   -> bar
//   C: gates MFMA + fused LSTM (exact R12 body)     -> bar (except last)
// ---------------------------------------------------------------------------
__global__ __launch_bounds__(512) void k_steps(
    const ushort* __restrict__ f16, const ushort* __restrict__ fa16,
    const float* __restrict__ W2, const float* __restrict__ b2,
    const float* __restrict__ V,
    const float* __restrict__ gxs,
    const ushort* __restrict__ wihh, const ushort* __restrict__ wihl,
    const ushort* __restrict__ whhh, const ushort* __restrict__ whhl,
    const float* __restrict__ b_ih, const float* __restrict__ b_hh,
    float* __restrict__ ha, float* __restrict__ logits,
    ushort* __restrict__ cth, ushort* __restrict__ ctl,
    ushort* __restrict__ hxp,
    float* __restrict__ hx, float* __restrict__ cx,
    float* __restrict__ hx_all, int* __restrict__ bar)
{
    __shared__ __align__(16) float smem[8736];   // 34.9 KB, phase-aliased
    const int tid = threadIdx.x;
    const int blk = blockIdx.x;
    const int lane = tid & 63;

    for (int t = 0; t < STEPS; ++t) {
        // ---------------- Phase A: ha[b][a] = hx[b].W2[a] + b2[a] ----------
        {
            const int a0 = (blk >> 3) * 16;
            const int b0 = (blk & 7) * 8;
            float* hx_s = smem;            // [8][1028]
            float* part = smem + 8224;     // 512
            for (int i = tid; i < 8 * 256; i += 512) {
                int r = i >> 8, c4 = i & 255;
                *(float4*)&hx_s[r * 1028 + c4 * 4] =
                    *(const float4*)(hx + (size_t)(b0 + r) * HID + c4 * 4);
            }
            __syncthreads();
            int a_i = tid >> 5, b_i = (tid >> 2) & 7, qq = tid & 3;
            const float4* wr = (const float4*)(W2 + (size_t)(a0 + a_i) * HID + qq * 256);
            const float* xr = &hx_s[b_i * 1028 + qq * 256];
            float s = 0.f;
            #pragma unroll 8
            for (int i = 0; i < 64; ++i) {
                float4 w = wr[i];
                float4 x = *(const float4*)(xr + i * 4);
                s += w.x*x.x + w.y*x.y + w.z*x.z + w.w*x.w;
            }
            part[tid] = s;
            __syncthreads();
            if (qq == 0)
                ha[(size_t)(b0 + b_i) * ATT + a0 + a_i] =
                    part[tid] + part[tid + 1] + part[tid + 2] + part[tid + 3] + b2[a0 + a_i];
        }
        gbar(bar);

        // ---------------- Phase B1: logits (b = blk>>2, 49 h's) ------------
        {
            const int b = blk >> 2, qh = blk & 3;
            float* ha_s = smem;            // 512
            float* V_s  = smem + 512;      // 512
            if (tid < ATT) { ha_s[tid] = ha[b * ATT + tid]; V_s[tid] = V[tid]; }
            __syncthreads();
            int wid = tid >> 6;
            for (int h = qh * 49 + wid; h < qh * 49 + 49; h += 8) {
                bfrag fv = *(const bfrag*)(fa16 + ((size_t)b * HW + h) * ATT + lane * 8);
                const float* hp = &ha_s[lane * 8];
                const float* vp = &V_s[lane * 8];
                float s = 0.f;
                #pragma unroll
                for (int j = 0; j < 8; ++j)
                    s += tanh_fast(bf2f((ushort)fv[j]) + hp[j]) * vp[j];
                #pragma unroll
                for (int off = 32; off > 0; off >>= 1) s += __shfl_down(s, off);
                if (lane == 0) logits[b * HW + h] = s;
            }
        }
        gbar(bar);

        // ---------------- Phase B2: softmax + ctx --------------------------
        {
            const int b = blk >> 2, eq = blk & 3;
            float* w_s  = smem;            // 196
            float* red  = smem + 256;      // 512
            float* part = smem + 768;      // 512
            float v = (tid < HW) ? logits[b * HW + tid] : -INFINITY;
            red[tid] = v;
            __syncthreads();
            for (int s2 = 256; s2 > 0; s2 >>= 1) {
                if (tid < s2) red[tid] = fmaxf(red[tid], red[tid + s2]);
                __syncthreads();
            }
            float mx = red[0];
            __syncthreads();
            float e = (tid < HW) ? __expf(v - mx) : 0.f;
            red[tid] = e;
            __syncthreads();
            for (int s2 = 256; s2 > 0; s2 >>= 1) {
                if (tid < s2) red[tid] += red[tid + s2];
                __syncthreads();
            }
            float inv = 1.0f / red[0];
            if (tid < HW) w_s[tid] = e * inv;
            __syncthreads();
            int el = tid & 127, hg = tid >> 7;
            int e0 = eq * 128 + el;
            const ushort* fb = f16 + (size_t)b * HW * EMB + e0;
            float s = 0.f;
            int h0 = hg * 49;
            for (int h = h0; h < h0 + 49; ++h)
                s = fmaf(w_s[h], bf2f(fb[(size_t)h * EMB]), s);
            part[tid] = s;
            __syncthreads();
            if (hg == 0) {
                float c = s + part[tid + 128] + part[tid + 256] + part[tid + 384];
                ushort ch = f2bf_rne(c);
                cth[b * EMB + e0] = ch;
                ctl[b * EMB + e0] = f2bf_rne(c - bf2f(ch));
            }
        }
        gbar(bar);

        // ---------------- Phase C: gates MFMA + fused LSTM -----------------
        {
            const ushort* hxh = hxp + (size_t)(t & 1) * 131072;
            const ushort* hxl = hxh + 65536;
            ushort* nxh = hxp + (size_t)((t + 1) & 1) * 131072;
            ushort* nxl = nxh + 65536;
            const float* gxs_t = gxs + (size_t)t * BB * 4096;
            float* hx_all_t = hx_all + (size_t)t * BB * HID;
            float (*sg)[64][16] = (float(*)[64][16])smem;   // 8 KB

            const int wid = tid >> 6;
            const int mt = wid & 3, kh = wid >> 2;
            const int l15 = lane & 15, g = lane >> 4;
            const int arow = mt * 16 + l15;
            const int ncol = (l15 >> 2) * 1024 + blk * 4 + (l15 & 3);
            const int koff = g * 8;

            f32x4 acc0 = {}, acc1 = {};

            if (kh == 0) {
                {   // ctx . W_ih[:, 512:1024)  (16 kk)
                    const ushort* ah = cth + (size_t)arow * 512 + koff;
                    const ushort* al = ctl + (size_t)arow * 512 + koff;
                    const ushort* bh = wihh + (size_t)ncol * 1024 + 512 + koff;
                    const ushort* bl = wihl + (size_t)ncol * 1024 + 512 + koff;
                    #pragma unroll 4
                    for (int kk = 0; kk < 16; ++kk) {
                        bfrag a_h = *(const bfrag*)(ah + kk * 32);
                        bfrag a_l = *(const bfrag*)(al + kk * 32);
                        bfrag b_h = *(const bfrag*)(bh + kk * 32);
                        bfrag b_l = *(const bfrag*)(bl + kk * 32);
                        acc0 = __builtin_amdgcn_mfma_f32_16x16x32_bf16(a_h, b_h, acc0, 0, 0, 0);
                        acc1 = __builtin_amdgcn_mfma_f32_16x16x32_bf16(a_h, b_l, acc1, 0, 0, 0);
                        acc1 = __builtin_amdgcn_mfma_f32_16x16x32_bf16(a_l, b_h, acc1, 0, 0, 0);
                    }
                }
                {   // hx[0:256) . W_hh[:, 0:256)  (8 kk)
                    const ushort* ah = hxh + (size_t)arow * 1024 + koff;
                    const ushort* al = hxl + (size_t)arow * 1024 + koff;
                    const ushort* bh = whhh + (size_t)ncol * 1024 + koff;
                    const ushort* bl = whhl + (size_t)ncol * 1024 + koff;
                    #pragma unroll 4
                    for (int kk = 0; kk < 8; ++kk) {
                        bfrag a_h = *(const bfrag*)(ah + kk * 32);
                        bfrag a_l = *(const bfrag*)(al + kk * 32);
                        bfrag b_h = *(const bfrag*)(bh + kk * 32);
                        bfrag b_l = *(const bfrag*)(bl + kk * 32);
                        acc0 = __builtin_amdgcn_mfma_f32_16x16x32_bf16(a_h, b_h, acc0, 0, 0, 0);
                        acc1 = __builtin_amdgcn_mfma_f32_16x16x32_bf16(a_h, b_l, acc1, 0, 0, 0);
                        acc1 = __builtin_amdgcn_mfma_f32_16x16x32_bf16(a_l, b_h, acc1, 0, 0, 0);
                    }
                }
            } else {
                // hx[256:1024) . W_hh[:, 256:1024)  (24 kk)
                const ushort* ah = hxh + (size_t)arow * 1024 + 256 + koff;
                const ushort* al = hxl + (size_t)arow * 1024 + 256 + koff;
                const ushort* bh = whhh + (size_t)ncol * 1024 + 256 + koff;
                const ushort* bl = whhl + (size_t)ncol * 1024 + 256 + koff;
                #pragma unroll 4
                for (int kk = 0; kk < 24; ++kk) {
                    bfrag a_h = *(const bfrag*)(ah + kk * 32);
                    bfrag a_l = *(const bfrag*)(al + kk * 32);
                    bfrag b_h = *(const bfrag*)(bh + kk * 32);
                    bfrag b_l = *(const bfrag*)(bl + kk * 32);
                    acc0 = __builtin_amdgcn_mfma_f32_16x16x32_bf16(a_h, b_h, acc0, 0, 0, 0);
                    acc1 = __builtin_amdgcn_mfma_f32_16x16x32_bf16(a_h, b_l, acc1, 0, 0, 0);
                    acc1 = __builtin_amdgcn_mfma_f32_16x16x32_bf16(a_l, b_h, acc1, 0, 0, 0);
                }
            }

            #pragma unroll
            for (int rr = 0; rr < 4; ++rr)
                sg[kh][mt * 16 + g * 4 + rr][l15] = acc0[rr] + acc1[rr];
            __syncthreads();

            if (tid < 256) {
                int b = tid >> 2, uu = tid & 3;
                int u = blk * 4 + uu;
                const float* gx = gxs_t + (size_t)b * 4096;
                float gi = sg[0][b][uu]      + sg[1][b][uu]      + gx[u]        + b_ih[u]        + b_hh[u];
                float gf = sg[0][b][4 + uu]  + sg[1][b][4 + uu]  + gx[1024 + u] + b_ih[1024 + u] + b_hh[1024 + u];
                float gg = sg[0][b][8 + uu]  + sg[1][b][8 + uu]  + gx[2048 + u] + b_ih[2048 + u] + b_hh[2048 + u];
                float go = sg[0][b][12 + uu] + sg[1][b][12 + uu] + gx[3072 + u] + b_ih[3072 + u] + b_hh[3072 + u];
                int idx = b * 1024 + u;
                float c = sigmoid_fast(gf) * cx[idx] + sigmoid_fast(gi) * tanh_fast(gg);
                float h = sigmoid_fast(go) * tanh_fast(c);
                cx[idx] = c;
                hx[idx] = h;
                hx_all_t[idx] = h;
                ushort hh = f2bf_rne(h);
                nxh[idx] = hh;
                nxl[idx] = f2bf_rne(h - bf2f(hh));
            }
        }
        if (t != STEPS - 1) gbar(bar);
    }
}

// ---------------------------------------------------------------------------
extern "C" void kernel_launch(void* const* d_in, const int* in_sizes, int n_in,
                              void* d_out, int out_size, void* d_ws, size_t ws_size,
                              hipStream_t stream) {
    const float* features = (const float*)d_in[0];
    const int*   captions = (const int*)d_in[1];
    const float* E      = (const float*)d_in[3];
    const float* W_feat = (const float*)d_in[4];
    const float* b_feat = (const float*)d_in[5];
    const float* W1     = (const float*)d_in[6];
    const float* b1     = (const float*)d_in[7];
    const float* W2     = (const float*)d_in[8];
    const float* b2     = (const float*)d_in[9];
    const float* V      = (const float*)d_in[10];
    // d_in[11] bV: softmax-invariant, unused
    const float* W_hi   = (const float*)d_in[12];
    const float* b_hi   = (const float*)d_in[13];
    const float* W_ci   = (const float*)d_in[14];
    const float* b_ci   = (const float*)d_in[15];
    const float* W_ih   = (const float*)d_in[16];
    const float* b_ih   = (const float*)d_in[17];
    const float* W_hh   = (const float*)d_in[18];
    const float* b_hh   = (const float*)d_in[19];
    const float* W_out  = (const float*)d_in[20];
    const float* b_out  = (const float*)d_in[21];
    float* out = (float*)d_out;

    // ---- workspace layout ----
    float* ws = (float*)d_ws;
    float* f_buf   = ws;                          // 6,422,528
    float* fa_buf  = f_buf + 6422528;             // 6,422,528
    float* fmean   = fa_buf + 6422528;            // 32,768
    float* hx      = fmean + 32768;               // 65,536
    float* cx      = hx + 65536;                  // 65,536
    float* hx_all  = cx + 65536;                  // 1,310,720
    float* ha      = hx_all + 1310720;            // 32,768
    float* logits  = ha + 32768;                  // 16,384 (padded)
    float* xs_f    = logits + 16384;              // 622,592
    float* gxs     = xs_f + 622592;               // 4,980,736
    int*   bar     = (int*)(gxs + 4980736);       // 1,024 ints
    ushort* p = (ushort*)(bar + 1024);
    ushort* wfeat_hi = p;            p += 1048576;
    ushort* wfeat_lo = p;            p += 1048576;
    ushort* w1_hi    = p;            p += 262144;
    ushort* w1_lo    = p;            p += 262144;
    ushort* wih_hi   = p;            p += 4194304;
    ushort* wih_lo   = p;            p += 4194304;
    ushort* whh_hi   = p;            p += 4194304;
    ushort* whh_lo   = p;            p += 4194304;
    ushort* ctx_hi   = p;            p += 32768;
    ushort* ctx_lo   = p;            p += 32768;
    ushort* hxp      = p;            p += 262144;   // [2 bufs][hi|lo][65536]
    ushort* f16      = p;            p += 6422528;
    ushort* fa16     = p;            p += 6422528;
    // W_out planes reuse f_buf+fa_buf region after the step loop
    ushort* wout_hi = (ushort*)f_buf;
    ushort* wout_lo = wout_hi + 10240000;

    // ---- precompute ----
    k_bar_init<<<1, 1024, 0, stream>>>(bar);
    k_split<<<1048576 / 4 / 256, 256, 0, stream>>>(W_feat, wfeat_hi, wfeat_lo, 1048576);
    k_split<<<262144 / 4 / 256, 256, 0, stream>>>(W1, w1_hi, w1_lo, 262144);
    k_split<<<4194304 / 4 / 256, 256, 0, stream>>>(W_ih, wih_hi, wih_lo, 4194304);
    k_split<<<4194304 / 4 / 256, 256, 0, stream>>>(W_hh, whh_hi, whh_lo, 4194304);
    k_embed<<<STEPS * BB, 128, 0, stream>>>(captions, E, xs_f);
    mfma_g<true, true><<<784, 256, 0, stream>>>(
        features, wfeat_hi, wfeat_lo, b_feat, f_buf, 512, 2048, 2048, 512, 4, 196);
    mfma_g<true, false><<<784, 256, 0, stream>>>(
        f_buf, w1_hi, w1_lo, b1, fa_buf, 512, 512, 512, 512, 4, 196);
    mfma_g<false, false><<<608, 256, 0, stream>>>(
        xs_f, wih_hi, wih_lo, nullptr, gxs, 4096, 512, 1024, 4096, 32, 19);
    k_cvt<<<6422528 / 4 / 256, 256, 0, stream>>>(f_buf, f16, 6422528);
    k_cvt<<<6422528 / 4 / 256, 256, 0, stream>>>(fa_buf, fa16, 6422528);
    k_fmean2<<<256, 256, 0, stream>>>(f_buf, fmean);
    k_init2<<<512, 256, 0, stream>>>(fmean, W_hi, b_hi, W_ci, b_ci,
                                     hx, cx, hxp, hxp + 65536);

    // ---- all 19 steps in one persistent kernel (fixed barrier) ----
    k_steps<<<256, 512, 0, stream>>>(
        f16, fa16, W2, b2, V, gxs,
        wih_hi, wih_lo, whh_hi, whh_lo, b_ih, b_hh,
        ha, logits, ctx_hi, ctx_lo, hxp, hx, cx, hx_all, bar);

    // ---- vocab projection over all steps: [1216,10000], K=1024 ----
    k_split<<<10240000 / 4 / 256, 256, 0, stream>>>(W_out, wout_hi, wout_lo, 10240000);
    mfma_g<false, false><<<1501, 256, 0, stream>>>(
        hx_all, wout_hi, wout_lo, b_out, out, VOCAB, HID, 1024, VOCAB, 79, 19);
}

// Round 18
// 1875.690 us; speedup vs baseline: 1.0951x; 1.0951x over previous
//
#include <hip/hip_runtime.h>
#include <hip/hip_bf16.h>
#include <math.h>

#define BB 64
#define HW 196
#define FEAT 2048
#define EMB 512
#define HID 1024
#define ATT 512
#define VOCAB 10000
#define TT 20
#define STEPS 19

using bfrag = __attribute__((ext_vector_type(8))) short;   // 8 bf16 = 4 VGPR
using f32x4 = __attribute__((ext_vector_type(4))) float;

__device__ __forceinline__ float sigmoid_fast(float x) { return 1.0f / (1.0f + __expf(-x)); }
__device__ __forceinline__ float tanh_fast(float x) {
    float e = __expf(2.0f * x);
    return 1.0f - 2.0f / (e + 1.0f);
}
__device__ __forceinline__ ushort f2bf_rne(float f) {
    unsigned u = __float_as_uint(f);
    unsigned r = (u + 0x7FFFu + ((u >> 16) & 1u)) >> 16;
    return (ushort)r;
}
__device__ __forceinline__ float bf2f(ushort h) {
    return __uint_as_float(((unsigned)h) << 16);
}
// XOR bank swizzle for 16B LDS chunks (R10-verified conflict-free).
__device__ __forceinline__ int sw_idx(int row, int g) { return row * 4 + (g ^ ((row >> 1) & 3)); }

// ---------------------------------------------------------------------------
__global__ __launch_bounds__(256) void k_split(const float* __restrict__ x,
                                               ushort* __restrict__ hi,
                                               ushort* __restrict__ lo, int n)
{
    int i4 = (blockIdx.x * 256 + threadIdx.x) * 4;
    if (i4 >= n) return;
    float4 v = *(const float4*)(x + i4);
    float av[4] = {v.x, v.y, v.z, v.w};
    #pragma unroll
    for (int j = 0; j < 4; ++j) {
        ushort h = f2bf_rne(av[j]);
        hi[i4 + j] = h;
        lo[i4 + j] = f2bf_rne(av[j] - bf2f(h));
    }
}

__global__ __launch_bounds__(256) void k_cvt(const float* __restrict__ x,
                                             ushort* __restrict__ y, int n)
{
    int i4 = (blockIdx.x * 256 + threadIdx.x) * 4;
    if (i4 >= n) return;
    float4 v = *(const float4*)(x + i4);
    *(ushort4*)(y + i4) = make_ushort4(f2bf_rne(v.x), f2bf_rne(v.y),
                                       f2bf_rne(v.z), f2bf_rne(v.w));
}

// ---------------------------------------------------------------------------
// mfma_g (R15/R16-verified).
// ---------------------------------------------------------------------------
template<bool NFAST, bool GLDS>
__global__ __launch_bounds__(256) void mfma_g(
    const float* __restrict__ A,
    const ushort* __restrict__ Bhi, const ushort* __restrict__ Blo,
    const float* __restrict__ bias, float* __restrict__ C,
    int N, int K, int Bld, int ldc, int NXB, int NMB)
{
    __shared__ __align__(16) ushort sAh[256 * 8];
    __shared__ __align__(16) ushort sAl[256 * 8];
    __shared__ __align__(16) ushort sBh[512 * 8];
    __shared__ __align__(16) ushort sBl[512 * 8];

    const int tid = threadIdx.x;

    const int nwg = NXB * NMB;
    const int q = nwg >> 3, r = nwg & 7;
    const int xcd = blockIdx.x & 7, sidx = blockIdx.x >> 3;
    const int wg = (xcd < r) ? (xcd * (q + 1) + sidx)
                             : (r * (q + 1) + (xcd - r) * q + sidx);
    int im, inb;
    if (NFAST) { inb = wg % NXB; im = wg / NXB; }
    else       { im = wg % NMB; inb = wg / NMB; }
    const int m0 = im * 64;
    const int n0 = inb * 128;

    const int lane = tid & 63;
    const int w = tid >> 6;
    const int mh = (w & 1) * 32;
    const int nh = (w >> 1) * 64;
    const int g = lane >> 4, l15 = lane & 15;

    const ushort* bsrc[4];
    ushort* bdst[4];
    if (GLDS) {
        #pragma unroll
        for (int i = 0; i < 4; ++i) {
            int cbase = i * 256 + w * 64;
            int plane = cbase >> 9;
            int ccb = cbase & 511;
            int cc = ccb + lane;
            int row = cc >> 2;
            int g_ = (cc & 3) ^ ((row >> 1) & 3);
            int brow = min(n0 + row, N - 1);
            bsrc[i] = (plane ? Blo : Bhi) + (size_t)brow * Bld + g_ * 8;
            bdst[i] = (plane ? sBl : sBh) + ccb * 8;
        }
    }

    f32x4 acc[2][4] = {};

    for (int k0 = 0; k0 < K; k0 += 32) {
        __syncthreads();
        {
            int r_ = tid >> 2, g_ = tid & 3;
            const float* ap = A + (size_t)(m0 + r_) * K + k0 + g_ * 8;
            float av[8];
            *(float4*)(av)     = *(const float4*)(ap);
            *(float4*)(av + 4) = *(const float4*)(ap + 4);
            bfrag vh, vl;
            #pragma unroll
            for (int j = 0; j < 8; ++j) {
                ushort h = f2bf_rne(av[j]);
                vh[j] = (short)h;
                vl[j] = (short)f2bf_rne(av[j] - bf2f(h));
            }
            int c = sw_idx(r_, g_) * 8;
            *(bfrag*)&sAh[c] = vh;
            *(bfrag*)&sAl[c] = vl;
        }
        if (GLDS) {
            #pragma unroll
            for (int i = 0; i < 4; ++i)
                __builtin_amdgcn_global_load_lds(
                    (const __attribute__((address_space(1))) void*)(bsrc[i] + k0),
                    (__attribute__((address_space(3))) void*)bdst[i], 16, 0, 0);
        } else {
            #pragma unroll
            for (int i = 0; i < 4; ++i) {
                int c = tid + i * 256;
                int pl = c >> 9, idx2 = c & 511;
                int r_ = idx2 >> 2, g_ = idx2 & 3;
                int brow = min(n0 + r_, N - 1);
                const ushort* src = (pl ? Blo : Bhi) + (size_t)brow * Bld + k0 + g_ * 8;
                int cc = sw_idx(r_, g_) * 8;
                if (pl) *(bfrag*)&sBl[cc] = *(const bfrag*)src;
                else    *(bfrag*)&sBh[cc] = *(const bfrag*)src;
            }
        }
        __syncthreads();

        bfrag ah[2], al[2], bh[4], bl[4];
        #pragma unroll
        for (int s = 0; s < 2; ++s) {
            int c = sw_idx(mh + s * 16 + l15, g) * 8;
            ah[s] = *(const bfrag*)&sAh[c];
            al[s] = *(const bfrag*)&sAl[c];
        }
        #pragma unroll
        for (int u = 0; u < 4; ++u) {
            int c = sw_idx(nh + u * 16 + l15, g) * 8;
            bh[u] = *(const bfrag*)&sBh[c];
            bl[u] = *(const bfrag*)&sBl[c];
        }
        #pragma unroll
        for (int s = 0; s < 2; ++s)
            #pragma unroll
            for (int u = 0; u < 4; ++u) {
                acc[s][u] = __builtin_amdgcn_mfma_f32_16x16x32_bf16(ah[s], bh[u], acc[s][u], 0, 0, 0);
                acc[s][u] = __builtin_amdgcn_mfma_f32_16x16x32_bf16(ah[s], bl[u], acc[s][u], 0, 0, 0);
                acc[s][u] = __builtin_amdgcn_mfma_f32_16x16x32_bf16(al[s], bh[u], acc[s][u], 0, 0, 0);
            }
    }

    #pragma unroll
    for (int s = 0; s < 2; ++s)
        #pragma unroll
        for (int u = 0; u < 4; ++u) {
            int col = n0 + nh + u * 16 + l15;
            if (col < N) {
                float bv = bias ? bias[col] : 0.f;
                #pragma unroll
                for (int rr = 0; rr < 4; ++rr) {
                    int row = m0 + mh + s * 16 + g * 4 + rr;
                    C[(size_t)row * ldc + col] = acc[s][u][rr] + bv;
                }
            }
        }
}

// ---------------------------------------------------------------------------
__global__ __launch_bounds__(256) void k_fmean2(const float* __restrict__ f,
                                                float* __restrict__ fmean)
{
    __shared__ float part[128];
    int blk = blockIdx.x;
    int b = blk >> 2, eq = blk & 3;
    int el = threadIdx.x & 127, half = threadIdx.x >> 7;
    int e = eq * 128 + el;
    const float* fb = f + (size_t)b * HW * EMB + e;
    float s = 0.f;
    int h0 = half * 98;
    for (int h = h0; h < h0 + 98; ++h) s += fb[(size_t)h * EMB];
    if (half) part[el] = s;
    __syncthreads();
    if (!half) fmean[b * EMB + e] = (s + part[el]) * (1.0f / HW);
}

__global__ __launch_bounds__(256) void k_init2(
    const float* __restrict__ fmean,
    const float* __restrict__ W_hi, const float* __restrict__ b_hi,
    const float* __restrict__ W_ci, const float* __restrict__ b_ci,
    float* __restrict__ hx, float* __restrict__ cx,
    ushort* __restrict__ hxp_h, ushort* __restrict__ hxp_l)
{
    int o = blockIdx.x * 256 + threadIdx.x;
    int b = o >> 11, uu = o & 2047;
    bool isC = uu >= 1024;
    int u = uu & 1023;
    const float4* wr = (const float4*)((isC ? W_ci : W_hi) + (size_t)u * EMB);
    const float4* fm = (const float4*)(fmean + (size_t)b * EMB);
    float s = isC ? b_ci[u] : b_hi[u];
    #pragma unroll 8
    for (int k = 0; k < EMB / 4; ++k) {
        float4 wv = wr[k], xv = fm[k];
        s += wv.x*xv.x + wv.y*xv.y + wv.z*xv.z + wv.w*xv.w;
    }
    int idx = b * HID + u;
    if (isC) cx[idx] = s;
    else {
        hx[idx] = s;
        ushort hh = f2bf_rne(s);
        hxp_h[idx] = hh;
        hxp_l[idx] = f2bf_rne(s - bf2f(hh));
    }
}

__global__ __launch_bounds__(128) void k_embed(const int* __restrict__ cap,
                                               const float* __restrict__ E,
                                               float* __restrict__ xs_f)
{
    int blk = blockIdx.x;
    int t = blk / BB, b = blk % BB;
    int c = cap[b * TT + t];
    const float4* src = (const float4*)(E + (size_t)c * EMB);
    float4* dst = (float4*)(xs_f + ((size_t)t * BB + b) * EMB);
    dst[threadIdx.x] = src[threadIdx.x];
}

// ---------------------------------------------------------------------------
// k_att2: one block per b (64 x 1024). Fuses ha computation (block-local,
// W2 L2/L3-resident) with logits -> softmax -> ctx -> split planes.
// ha phase: wave w handles a = w, w+16, ... (32 a's/wave); K=1024 dot
// split over 64 lanes x 4 float4 + shfl reduce (R5-phase1-verified pattern).
// ---------------------------------------------------------------------------
__global__ __launch_bounds__(1024) void k_att2(
    const ushort* __restrict__ f16, const ushort* __restrict__ fa16,
    const float* __restrict__ hx,
    const float* __restrict__ W2, const float* __restrict__ b2,
    const float* __restrict__ V,
    ushort* __restrict__ ctx_hi, ushort* __restrict__ ctx_lo)
{
    __shared__ __align__(16) float smem[3072];
    const int b = blockIdx.x;
    const int tid = threadIdx.x;
    const int lane = tid & 63;
    const int wid = tid >> 6;

    float* hx_s = smem;          // 1024
    float* ha_s = smem + 1024;   // 512
    float* V_s  = smem + 1536;   // 512
    float* w_s  = smem + 2048;   // 256 (196 used)
    float* red  = smem + 2304;   // 256
    float* pc   = smem + 2560;   // 512

    hx_s[tid] = hx[b * HID + tid];
    if (tid < ATT) V_s[tid] = V[tid];
    __syncthreads();

    // ha[a] = hx[b] . W2[a] + b2[a]
    for (int a = wid; a < ATT; a += 16) {
        const float4* wr = (const float4*)(W2 + (size_t)a * HID);
        float s = 0.f;
        #pragma unroll
        for (int qv = 0; qv < 4; ++qv) {
            int i4 = qv * 64 + lane;
            float4 w = wr[i4];
            float4 x = *(const float4*)&hx_s[i4 * 4];
            s += w.x*x.x + w.y*x.y + w.z*x.z + w.w*x.w;
        }
        #pragma unroll
        for (int off = 32; off > 0; off >>= 1) s += __shfl_down(s, off);
        if (lane == 0) ha_s[a] = s + b2[a];
    }
    __syncthreads();

    // logits
    for (int h = wid; h < HW; h += 16) {
        bfrag fv = *(const bfrag*)(fa16 + ((size_t)b * HW + h) * ATT + lane * 8);
        const float* hp = &ha_s[lane * 8];
        const float* vp = &V_s[lane * 8];
        float s = 0.f;
        #pragma unroll
        for (int j = 0; j < 8; ++j)
            s += tanh_fast(bf2f((ushort)fv[j]) + hp[j]) * vp[j];
        #pragma unroll
        for (int off = 32; off > 0; off >>= 1) s += __shfl_down(s, off);
        if (lane == 0) w_s[h] = s;
    }
    __syncthreads();

    // softmax over 196
    float v = (tid < HW) ? w_s[tid] : -INFINITY;
    if (tid < 256) red[tid] = v;
    __syncthreads();
    for (int s2 = 128; s2 > 0; s2 >>= 1) {
        if (tid < s2) red[tid] = fmaxf(red[tid], red[tid + s2]);
        __syncthreads();
    }
    float mx = red[0];
    __syncthreads();
    float e = (tid < HW) ? __expf(v - mx) : 0.f;
    if (tid < 256) red[tid] = e;
    __syncthreads();
    for (int s2 = 128; s2 > 0; s2 >>= 1) {
        if (tid < s2) red[tid] += red[tid + s2];
        __syncthreads();
    }
    float inv = 1.0f / red[0];
    if (tid < HW) w_s[tid] = e * inv;
    __syncthreads();

    // ctx
    {
        int e0 = tid & 511, grp = tid >> 9;
        const ushort* fb = f16 + (size_t)b * HW * EMB + e0;
        float s = 0.f;
        int h0 = grp * 98;
        for (int h = h0; h < h0 + 98; ++h)
            s = fmaf(w_s[h], bf2f(fb[(size_t)h * EMB]), s);
        if (grp) pc[e0] = s;
        __syncthreads();
        if (!grp) {
            float c = s + pc[e0];
            ushort ch = f2bf_rne(c);
            ctx_hi[b * EMB + e0] = ch;
            ctx_lo[b * EMB + e0] = f2bf_rne(c - bf2f(ch));
        }
    }
}

// ---------------------------------------------------------------------------
// k_gates_lstm (R12-verified, unchanged).
// ---------------------------------------------------------------------------
__global__ __launch_bounds__(512) void k_gates_lstm(
    const float* __restrict__ gxs_t,
    const ushort* __restrict__ cth, const ushort* __restrict__ ctl,
    const ushort* __restrict__ hxh, const ushort* __restrict__ hxl,
    const ushort* __restrict__ wihh, const ushort* __restrict__ wihl,
    const ushort* __restrict__ whhh, const ushort* __restrict__ whhl,
    const float* __restrict__ b_ih, const float* __restrict__ b_hh,
    float* __restrict__ hx, float* __restrict__ cx,
    ushort* __restrict__ nxh, ushort* __restrict__ nxl,
    float* __restrict__ hx_all_t)
{
    __shared__ float sg[2][64][16];   // 8 KB
    const int tid = threadIdx.x, bk = blockIdx.x;
    const int lane = tid & 63, wid = tid >> 6;
    const int mt = wid & 3, kh = wid >> 2;
    const int l15 = lane & 15, g = lane >> 4;
    const int arow = mt * 16 + l15;
    const int ncol = (l15 >> 2) * 1024 + bk * 4 + (l15 & 3);
    const int koff = g * 8;

    f32x4 acc0 = {}, acc1 = {};

    if (kh == 0) {
        {   // ctx . W_ih[:, 512:1024)  (16 kk)
            const ushort* ah = cth + (size_t)arow * 512 + koff;
            const ushort* al = ctl + (size_t)arow * 512 + koff;
            const ushort* bh = wihh + (size_t)ncol * 1024 + 512 + koff;
            const ushort* bl = wihl + (size_t)ncol * 1024 + 512 + koff;
            #pragma unroll 4
            for (int kk = 0; kk < 16; ++kk) {
                bfrag a_h = *(const bfrag*)(ah + kk * 32);
                bfrag a_l = *(const bfrag*)(al + kk * 32);
                bfrag b_h = *(const bfrag*)(bh + kk * 32);
                bfrag b_l = *(const bfrag*)(bl + kk * 32);
                acc0 = __builtin_amdgcn_mfma_f32_16x16x32_bf16(a_h, b_h, acc0, 0, 0, 0);
                acc1 = __builtin_amdgcn_mfma_f32_16x16x32_bf16(a_h, b_l, acc1, 0, 0, 0);
                acc1 = __builtin_amdgcn_mfma_f32_16x16x32_bf16(a_l, b_h, acc1, 0, 0, 0);
            }
        }
        {   // hx[0:256) . W_hh[:, 0:256)  (8 kk)
            const ushort* ah = hxh + (size_t)arow * 1024 + koff;
            const ushort* al = hxl + (size_t)arow * 1024 + koff;
            const ushort* bh = whhh + (size_t)ncol * 1024 + koff;
            const ushort* bl = whhl + (size_t)ncol * 1024 + koff;
            #pragma unroll 4
            for (int kk = 0; kk < 8; ++kk) {
                bfrag a_h = *(const bfrag*)(ah + kk * 32);
                bfrag a_l = *(const bfrag*)(al + kk * 32);
                bfrag b_h = *(const bfrag*)(bh + kk * 32);
                bfrag b_l = *(const bfrag*)(bl + kk * 32);
                acc0 = __builtin_amdgcn_mfma_f32_16x16x32_bf16(a_h, b_h, acc0, 0, 0, 0);
                acc1 = __builtin_amdgcn_mfma_f32_16x16x32_bf16(a_h, b_l, acc1, 0, 0, 0);
                acc1 = __builtin_amdgcn_mfma_f32_16x16x32_bf16(a_l, b_h, acc1, 0, 0, 0);
            }
        }
    } else {
        // hx[256:1024) . W_hh[:, 256:1024)  (24 kk)
        const ushort* ah = hxh + (size_t)arow * 1024 + 256 + koff;
        const ushort* al = hxl + (size_t)arow * 1024 + 256 + koff;
        const ushort* bh = whhh + (size_t)ncol * 1024 + 256 + koff;
        const ushort* bl = whhl + (size_t)ncol * 1024 + 256 + koff;
        #pragma unroll 4
        for (int kk = 0; kk < 24; ++kk) {
            bfrag a_h = *(const bfrag*)(ah + kk * 32);
            bfrag a_l = *(const bfrag*)(al + kk * 32);
            bfrag b_h = *(const bfrag*)(bh + kk * 32);
            bfrag b_l = *(const bfrag*)(bl + kk * 32);
            acc0 = __builtin_amdgcn_mfma_f32_16x16x32_bf16(a_h, b_h, acc0, 0, 0, 0);
            acc1 = __builtin_amdgcn_mfma_f32_16x16x32_bf16(a_h, b_l, acc1, 0, 0, 0);
            acc1 = __builtin_amdgcn_mfma_f32_16x16x32_bf16(a_l, b_h, acc1, 0, 0, 0);
        }
    }

    #pragma unroll
    for (int rr = 0; rr < 4; ++rr)
        sg[kh][mt * 16 + g * 4 + rr][l15] = acc0[rr] + acc1[rr];
    __syncthreads();

    if (tid < 256) {
        int b = tid >> 2, uu = tid & 3;
        int u = bk * 4 + uu;
        const float* gx = gxs_t + (size_t)b * 4096;
        float gi = sg[0][b][uu]      + sg[1][b][uu]      + gx[u]        + b_ih[u]        + b_hh[u];
        float gf = sg[0][b][4 + uu]  + sg[1][b][4 + uu]  + gx[1024 + u] + b_ih[1024 + u] + b_hh[1024 + u];
        float gg = sg[0][b][8 + uu]  + sg[1][b][8 + uu]  + gx[2048 + u] + b_ih[2048 + u] + b_hh[2048 + u];
        float go = sg[0][b][12 + uu] + sg[1][b][12 + uu] + gx[3072 + u] + b_ih[3072 + u] + b_hh[3072 + u];
        int idx = b * 1024 + u;
        float c = sigmoid_fast(gf) * cx[idx] + sigmoid_fast(gi) * tanh_fast(gg);
        float h = sigmoid_fast(go) * tanh_fast(c);
        cx[idx] = c;
        hx[idx] = h;
        hx_all_t[idx] = h;
        ushort hh = f2bf_rne(h);
        nxh[idx] = hh;
        nxl[idx] = f2bf_rne(h - bf2f(hh));
    }
}

// ---------------------------------------------------------------------------
extern "C" void kernel_launch(void* const* d_in, const int* in_sizes, int n_in,
                              void* d_out, int out_size, void* d_ws, size_t ws_size,
                              hipStream_t stream) {
    const float* features = (const float*)d_in[0];
    const int*   captions = (const int*)d_in[1];
    const float* E      = (const float*)d_in[3];
    const float* W_feat = (const float*)d_in[4];
    const float* b_feat = (const float*)d_in[5];
    const float* W1     = (const float*)d_in[6];
    const float* b1     = (const float*)d_in[7];
    const float* W2     = (const float*)d_in[8];
    const float* b2     = (const float*)d_in[9];
    const float* V      = (const float*)d_in[10];
    // d_in[11] bV: softmax-invariant, unused
    const float* W_hi   = (const float*)d_in[12];
    const float* b_hi   = (const float*)d_in[13];
    const float* W_ci   = (const float*)d_in[14];
    const float* b_ci   = (const float*)d_in[15];
    const float* W_ih   = (const float*)d_in[16];
    const float* b_ih   = (const float*)d_in[17];
    const float* W_hh   = (const float*)d_in[18];
    const float* b_hh   = (const float*)d_in[19];
    const float* W_out  = (const float*)d_in[20];
    const float* b_out  = (const float*)d_in[21];
    float* out = (float*)d_out;

    // ---- workspace layout (R16 + no ha buffer) ----
    float* ws = (float*)d_ws;
    float* f_buf   = ws;                          // 6,422,528
    float* fa_buf  = f_buf + 6422528;             // 6,422,528
    float* fmean   = fa_buf + 6422528;            // 32,768
    float* hx      = fmean + 32768;               // 65,536
    float* cx      = hx + 65536;                  // 65,536
    float* hx_all  = cx + 65536;                  // 1,310,720
    float* xs_f    = hx_all + 1310720;            // 622,592
    float* gxs     = xs_f + 622592;               // 4,980,736
    ushort* p = (ushort*)(gxs + 4980736);
    ushort* wfeat_hi = p;            p += 1048576;
    ushort* wfeat_lo = p;            p += 1048576;
    ushort* w1_hi    = p;            p += 262144;
    ushort* w1_lo    = p;            p += 262144;
    ushort* wih_hi   = p;            p += 4194304;
    ushort* wih_lo   = p;            p += 4194304;
    ushort* whh_hi   = p;            p += 4194304;
    ushort* whh_lo   = p;            p += 4194304;
    ushort* ctx_hi   = p;            p += 32768;
    ushort* ctx_lo   = p;            p += 32768;
    ushort* hxp      = p;            p += 262144;   // [2 bufs][hi|lo][65536]
    ushort* f16      = p;            p += 6422528;
    ushort* fa16     = p;            p += 6422528;
    // W_out planes reuse f_buf+fa_buf region after the step loop
    ushort* wout_hi = (ushort*)f_buf;
    ushort* wout_lo = wout_hi + 10240000;

    // ---- precompute ----
    k_split<<<1048576 / 4 / 256, 256, 0, stream>>>(W_feat, wfeat_hi, wfeat_lo, 1048576);
    k_split<<<262144 / 4 / 256, 256, 0, stream>>>(W1, w1_hi, w1_lo, 262144);
    k_split<<<4194304 / 4 / 256, 256, 0, stream>>>(W_ih, wih_hi, wih_lo, 4194304);
    k_split<<<4194304 / 4 / 256, 256, 0, stream>>>(W_hh, whh_hi, whh_lo, 4194304);
    k_embed<<<STEPS * BB, 128, 0, stream>>>(captions, E, xs_f);
    mfma_g<true, true><<<784, 256, 0, stream>>>(
        features, wfeat_hi, wfeat_lo, b_feat, f_buf, 512, 2048, 2048, 512, 4, 196);
    mfma_g<true, false><<<784, 256, 0, stream>>>(
        f_buf, w1_hi, w1_lo, b1, fa_buf, 512, 512, 512, 512, 4, 196);
    mfma_g<false, false><<<608, 256, 0, stream>>>(
        xs_f, wih_hi, wih_lo, nullptr, gxs, 4096, 512, 1024, 4096, 32, 19);
    k_cvt<<<6422528 / 4 / 256, 256, 0, stream>>>(f_buf, f16, 6422528);
    k_cvt<<<6422528 / 4 / 256, 256, 0, stream>>>(fa_buf, fa16, 6422528);
    k_fmean2<<<256, 256, 0, stream>>>(f_buf, fmean);
    k_init2<<<512, 256, 0, stream>>>(fmean, W_hi, b_hi, W_ci, b_ci,
                                     hx, cx, hxp, hxp + 65536);

    // ---- recurrent steps: 2 dispatches per step ----
    for (int t = 0; t < STEPS; ++t) {
        ushort* hx_rd = hxp + (size_t)(t & 1) * 131072;
        ushort* hx_wr = hxp + (size_t)((t + 1) & 1) * 131072;
        k_att2<<<BB, 1024, 0, stream>>>(f16, fa16, hx, W2, b2, V, ctx_hi, ctx_lo);
        k_gates_lstm<<<256, 512, 0, stream>>>(
            gxs + (size_t)t * BB * 4096,
            ctx_hi, ctx_lo, hx_rd, hx_rd + 65536,
            wih_hi, wih_lo, whh_hi, whh_lo, b_ih, b_hh,
            hx, cx, hx_wr, hx_wr + 65536,
            hx_all + (size_t)t * BB * HID);
    }

    // ---- vocab projection over all steps: [1216,10000], K=1024 ----
    k_split<<<10240000 / 4 / 256, 256, 0, stream>>>(W_out, wout_hi, wout_lo, 10240000);
    mfma_g<false, false><<<1501, 256, 0, stream>>>(
        hx_all, wout_hi, wout_lo, b_out, out, VOCAB, HID, 1024, VOCAB, 79, 19);
}

// Round 19
// 1572.498 us; speedup vs baseline: 1.3063x; 1.1928x over previous
//
#include <hip/hip_runtime.h>
#include <hip/hip_bf16.h>
#include <math.h>

#define BB 64
#define HW 196
#define FEAT 2048
#define EMB 512
#define HID 1024
#define ATT 512
#define VOCAB 10000
#define TT 20
#define STEPS 19

using bfrag = __attribute__((ext_vector_type(8))) short;   // 8 bf16 = 4 VGPR
using f32x4 = __attribute__((ext_vector_type(4))) float;

__device__ __forceinline__ float sigmoid_fast(float x) { return 1.0f / (1.0f + __expf(-x)); }
__device__ __forceinline__ float tanh_fast(float x) {
    float e = __expf(2.0f * x);
    return 1.0f - 2.0f / (e + 1.0f);
}
__device__ __forceinline__ ushort f2bf_rne(float f) {
    unsigned u = __float_as_uint(f);
    unsigned r = (u + 0x7FFFu + ((u >> 16) & 1u)) >> 16;
    return (ushort)r;
}
__device__ __forceinline__ float bf2f(ushort h) {
    return __uint_as_float(((unsigned)h) << 16);
}
// XOR bank swizzle for 16B LDS chunks (R10-verified conflict-free):
// chunk = row*4 + (g ^ ((row>>1)&3)); slot within any 8-lane window is a
// permutation of 0..7 on both staging writes and fragment reads.
__device__ __forceinline__ int sw_idx(int row, int g) { return row * 4 + (g ^ ((row >> 1) & 3)); }

// ---------------------------------------------------------------------------
// fp32 -> split bf16 planes: x = hi + lo.  n % 1024 == 0.
// ---------------------------------------------------------------------------
__global__ __launch_bounds__(256) void k_split(const float* __restrict__ x,
                                               ushort* __restrict__ hi,
                                               ushort* __restrict__ lo, int n)
{
    int i4 = (blockIdx.x * 256 + threadIdx.x) * 4;
    if (i4 >= n) return;
    float4 v = *(const float4*)(x + i4);
    float av[4] = {v.x, v.y, v.z, v.w};
    #pragma unroll
    for (int j = 0; j < 4; ++j) {
        ushort h = f2bf_rne(av[j]);
        hi[i4 + j] = h;
        lo[i4 + j] = f2bf_rne(av[j] - bf2f(h));
    }
}

// ---------------------------------------------------------------------------
// mfma_g (best-verified config): split-bf16 NT GEMM, 64(M) x 128(N),
// BK=32, 4 waves. 3-term. A fp32 (split during reg staging); B pre-split
// planes, leading dim Bld. LDS XOR-swizzled (sw_idx). T1 XCD swizzle.
// NFAST: m-panel-local block order; else n-panel-local.
// GLDS: B staged via global_load_lds (linear dest + inverse-swizzled
// per-lane source). Enabled ONLY for the f GEMM (B L2-resident; measured
// 148 -> 138 us consistently across R13/R14/R15).
// ---------------------------------------------------------------------------
template<bool NFAST, bool GLDS>
__global__ __launch_bounds__(256) void mfma_g(
    const float* __restrict__ A,
    const ushort* __restrict__ Bhi, const ushort* __restrict__ Blo,
    const float* __restrict__ bias, float* __restrict__ C,
    int N, int K, int Bld, int ldc, int NXB, int NMB)
{
    __shared__ __align__(16) ushort sAh[256 * 8];
    __shared__ __align__(16) ushort sAl[256 * 8];
    __shared__ __align__(16) ushort sBh[512 * 8];
    __shared__ __align__(16) ushort sBl[512 * 8];

    const int tid = threadIdx.x;

    const int nwg = NXB * NMB;
    const int q = nwg >> 3, r = nwg & 7;
    const int xcd = blockIdx.x & 7, sidx = blockIdx.x >> 3;
    const int wg = (xcd < r) ? (xcd * (q + 1) + sidx)
                             : (r * (q + 1) + (xcd - r) * q + sidx);
    int im, inb;
    if (NFAST) { inb = wg % NXB; im = wg / NXB; }
    else       { im = wg % NMB; inb = wg / NMB; }
    const int m0 = im * 64;
    const int n0 = inb * 128;

    const int lane = tid & 63;
    const int w = tid >> 6;
    const int mh = (w & 1) * 32;
    const int nh = (w >> 1) * 64;
    const int g = lane >> 4, l15 = lane & 15;

    // B gload_lds descriptors (GLDS only)
    const ushort* bsrc[4];
    ushort* bdst[4];
    if (GLDS) {
        #pragma unroll
        for (int i = 0; i < 4; ++i) {
            int cbase = i * 256 + w * 64;      // wave-uniform
            int plane = cbase >> 9;
            int ccb = cbase & 511;
            int cc = ccb + lane;
            int row = cc >> 2;
            int g_ = (cc & 3) ^ ((row >> 1) & 3);
            int brow = min(n0 + row, N - 1);
            bsrc[i] = (plane ? Blo : Bhi) + (size_t)brow * Bld + g_ * 8;
            bdst[i] = (plane ? sBl : sBh) + ccb * 8;
        }
    }

    f32x4 acc[2][4] = {};

    for (int k0 = 0; k0 < K; k0 += 32) {
        __syncthreads();
        {   // A: fp32 -> hi/lo, swizzled store
            int r_ = tid >> 2, g_ = tid & 3;
            const float* ap = A + (size_t)(m0 + r_) * K + k0 + g_ * 8;
            float av[8];
            *(float4*)(av)     = *(const float4*)(ap);
            *(float4*)(av + 4) = *(const float4*)(ap + 4);
            bfrag vh, vl;
            #pragma unroll
            for (int j = 0; j < 8; ++j) {
                ushort h = f2bf_rne(av[j]);
                vh[j] = (short)h;
                vl[j] = (short)f2bf_rne(av[j] - bf2f(h));
            }
            int c = sw_idx(r_, g_) * 8;
            *(bfrag*)&sAh[c] = vh;
            *(bfrag*)&sAl[c] = vl;
        }
        if (GLDS) {
            #pragma unroll
            for (int i = 0; i < 4; ++i)
                __builtin_amdgcn_global_load_lds(
                    (const __attribute__((address_space(1))) void*)(bsrc[i] + k0),
                    (__attribute__((address_space(3))) void*)bdst[i], 16, 0, 0);
        } else {
            #pragma unroll
            for (int i = 0; i < 4; ++i) {   // B planes, swizzled store
                int c = tid + i * 256;
                int pl = c >> 9, idx2 = c & 511;
                int r_ = idx2 >> 2, g_ = idx2 & 3;
                int brow = min(n0 + r_, N - 1);
                const ushort* src = (pl ? Blo : Bhi) + (size_t)brow * Bld + k0 + g_ * 8;
                int cc = sw_idx(r_, g_) * 8;
                if (pl) *(bfrag*)&sBl[cc] = *(const bfrag*)src;
                else    *(bfrag*)&sBh[cc] = *(const bfrag*)src;
            }
        }
        __syncthreads();

        bfrag ah[2], al[2], bh[4], bl[4];
        #pragma unroll
        for (int s = 0; s < 2; ++s) {
            int c = sw_idx(mh + s * 16 + l15, g) * 8;
            ah[s] = *(const bfrag*)&sAh[c];
            al[s] = *(const bfrag*)&sAl[c];
        }
        #pragma unroll
        for (int u = 0; u < 4; ++u) {
            int c = sw_idx(nh + u * 16 + l15, g) * 8;
            bh[u] = *(const bfrag*)&sBh[c];
            bl[u] = *(const bfrag*)&sBl[c];
        }
        #pragma unroll
        for (int s = 0; s < 2; ++s)
            #pragma unroll
            for (int u = 0; u < 4; ++u) {
                acc[s][u] = __builtin_amdgcn_mfma_f32_16x16x32_bf16(ah[s], bh[u], acc[s][u], 0, 0, 0);
                acc[s][u] = __builtin_amdgcn_mfma_f32_16x16x32_bf16(ah[s], bl[u], acc[s][u], 0, 0, 0);
                acc[s][u] = __builtin_amdgcn_mfma_f32_16x16x32_bf16(al[s], bh[u], acc[s][u], 0, 0, 0);
            }
    }

    #pragma unroll
    for (int s = 0; s < 2; ++s)
        #pragma unroll
        for (int u = 0; u < 4; ++u) {
            int col = n0 + nh + u * 16 + l15;
            if (col < N) {
                float bv = bias ? bias[col] : 0.f;
                #pragma unroll
                for (int rr = 0; rr < 4; ++rr) {
                    int row = m0 + mh + s * 16 + g * 4 + rr;
                    C[(size_t)row * ldc + col] = acc[s][u][rr] + bv;
                }
            }
        }
}

// ---------------------------------------------------------------------------
__global__ __launch_bounds__(256) void k_fmean2(const float* __restrict__ f,
                                                float* __restrict__ fmean)
{
    __shared__ float part[128];
    int blk = blockIdx.x;
    int b = blk >> 2, eq = blk & 3;
    int el = threadIdx.x & 127, half = threadIdx.x >> 7;
    int e = eq * 128 + el;
    const float* fb = f + (size_t)b * HW * EMB + e;
    float s = 0.f;
    int h0 = half * 98;
    for (int h = h0; h < h0 + 98; ++h) s += fb[(size_t)h * EMB];
    if (half) part[el] = s;
    __syncthreads();
    if (!half) fmean[b * EMB + e] = (s + part[el]) * (1.0f / HW);
}

__global__ __launch_bounds__(256) void k_init2(
    const float* __restrict__ fmean,
    const float* __restrict__ W_hi, const float* __restrict__ b_hi,
    const float* __restrict__ W_ci, const float* __restrict__ b_ci,
    float* __restrict__ hx, float* __restrict__ cx,
    ushort* __restrict__ hxp_h, ushort* __restrict__ hxp_l)
{
    int o = blockIdx.x * 256 + threadIdx.x;   // 0..131071
    int b = o >> 11, uu = o & 2047;
    bool isC = uu >= 1024;
    int u = uu & 1023;
    const float4* wr = (const float4*)((isC ? W_ci : W_hi) + (size_t)u * EMB);
    const float4* fm = (const float4*)(fmean + (size_t)b * EMB);
    float s = isC ? b_ci[u] : b_hi[u];
    #pragma unroll 8
    for (int k = 0; k < EMB / 4; ++k) {
        float4 wv = wr[k], xv = fm[k];
        s += wv.x*xv.x + wv.y*xv.y + wv.z*xv.z + wv.w*xv.w;
    }
    int idx = b * HID + u;
    if (isC) cx[idx] = s;
    else {
        hx[idx] = s;
        ushort hh = f2bf_rne(s);
        hxp_h[idx] = hh;
        hxp_l[idx] = f2bf_rne(s - bf2f(hh));
    }
}

__global__ __launch_bounds__(128) void k_embed(const int* __restrict__ cap,
                                               const float* __restrict__ E,
                                               float* __restrict__ xs_f)
{
    int blk = blockIdx.x;
    int t = blk / BB, b = blk % BB;
    int c = cap[b * TT + t];
    const float4* src = (const float4*)(E + (size_t)c * EMB);
    float4* dst = (float4*)(xs_f + ((size_t)t * BB + b) * EMB);
    dst[threadIdx.x] = src[threadIdx.x];
}

// ---------------------------------------------------------------------------
// k_ha: ha[b][a] = hx[b].W2[a] + b2[a].  grid 256: block -> 16 a's x 8 b's.
// ---------------------------------------------------------------------------
__global__ __launch_bounds__(256) void k_ha(
    const float* __restrict__ hx, const float* __restrict__ W2,
    const float* __restrict__ b2, float* __restrict__ ha)
{
    __shared__ __align__(16) float hx_s[8][1028];
    __shared__ float part[256];
    const int tid = threadIdx.x;
    const int a0 = (blockIdx.x >> 3) * 16;
    const int b0 = (blockIdx.x & 7) * 8;

    for (int i = tid; i < 8 * 256; i += 256) {
        int r = i >> 8, c4 = i & 255;
        *(float4*)&hx_s[r][c4 * 4] = *(const float4*)(hx + (size_t)(b0 + r) * HID + c4 * 4);
    }
    __syncthreads();

    const int a_i = tid >> 4;
    const int b_i = (tid >> 1) & 7;
    const int half = tid & 1;
    const float4* wr = (const float4*)(W2 + (size_t)(a0 + a_i) * HID + half * 512);
    const float* xr = &hx_s[b_i][half * 512];
    float s = 0.f;
    #pragma unroll 8
    for (int i = 0; i < 128; ++i) {
        float4 w = wr[i];
        float4 x = *(const float4*)(xr + i * 4);
        s += w.x*x.x + w.y*x.y + w.z*x.z + w.w*x.w;
    }
    part[tid] = s;
    __syncthreads();
    if (!half)
        ha[(size_t)(b0 + b_i) * ATT + a0 + a_i] = part[tid] + part[tid + 1] + b2[a0 + a_i];
}

// ---------------------------------------------------------------------------
// k_att (R12-verified form): one block per b (64 x 1024):
// logits (fa fp32) -> softmax -> ctx -> split planes.
// ---------------------------------------------------------------------------
__global__ __launch_bounds__(1024) void k_att(
    const float* __restrict__ f, const float* __restrict__ fa,
    const float* __restrict__ ha, const float* __restrict__ V,
    ushort* __restrict__ ctx_hi, ushort* __restrict__ ctx_lo)
{
    __shared__ __align__(16) float smem[2048];
    const int b = blockIdx.x;
    const int tid = threadIdx.x;
    const int lane = tid & 63;
    const int wid = tid >> 6;

    float* ha_s = smem;          // 512
    float* V_s  = smem + 512;    // 512
    float* w_s  = smem + 1024;   // 256 (196 used)
    float* red  = smem + 1280;   // 256
    float* pc   = smem + 1536;   // 512

    if (tid < ATT) { ha_s[tid] = ha[b * ATT + tid]; V_s[tid] = V[tid]; }
    __syncthreads();

    for (int h = wid; h < HW; h += 16) {
        const float4* fr = (const float4*)(fa + ((size_t)b * HW + h) * ATT);
        float s = 0.f;
        #pragma unroll
        for (int q = 0; q < 2; ++q) {
            int i4 = q * 64 + lane;
            float4 fv = fr[i4];
            float4 hv = *(const float4*)&ha_s[i4 * 4];
            float4 vv = *(const float4*)&V_s[i4 * 4];
            s += tanh_fast(fv.x + hv.x) * vv.x + tanh_fast(fv.y + hv.y) * vv.y
               + tanh_fast(fv.z + hv.z) * vv.z + tanh_fast(fv.w + hv.w) * vv.w;
        }
        #pragma unroll
        for (int off = 32; off > 0; off >>= 1) s += __shfl_down(s, off);
        if (lane == 0) w_s[h] = s;
    }
    __syncthreads();

    float v = (tid < HW) ? w_s[tid] : -INFINITY;
    if (tid < 256) red[tid] = v;
    __syncthreads();
    for (int s2 = 128; s2 > 0; s2 >>= 1) {
        if (tid < s2) red[tid] = fmaxf(red[tid], red[tid + s2]);
        __syncthreads();
    }
    float mx = red[0];
    __syncthreads();
    float e = (tid < HW) ? __expf(v - mx) : 0.f;
    if (tid < 256) red[tid] = e;
    __syncthreads();
    for (int s2 = 128; s2 > 0; s2 >>= 1) {
        if (tid < s2) red[tid] += red[tid + s2];
        __syncthreads();
    }
    float inv = 1.0f / red[0];
    if (tid < HW) w_s[tid] = e * inv;
    __syncthreads();

    {
        int e0 = tid & 511, grp = tid >> 9;
        const float* fb = f + (size_t)b * HW * EMB + e0;
        float s = 0.f;
        int h0 = grp * 98;
        for (int h = h0; h < h0 + 98; ++h)
            s = fmaf(w_s[h], fb[(size_t)h * EMB], s);
        if (grp) pc[e0] = s;
        __syncthreads();
        if (!grp) {
            float c = s + pc[e0];
            ushort ch = f2bf_rne(c);
            ctx_hi[b * EMB + e0] = ch;
            ctx_lo[b * EMB + e0] = f2bf_rne(c - bf2f(ch));
        }
    }
}

// ---------------------------------------------------------------------------
// k_gates_lstm (R12-verified, unchanged).
// ---------------------------------------------------------------------------
__global__ __launch_bounds__(512) void k_gates_lstm(
    const float* __restrict__ gxs_t,
    const ushort* __restrict__ cth, const ushort* __restrict__ ctl,
    const ushort* __restrict__ hxh, const ushort* __restrict__ hxl,
    const ushort* __restrict__ wihh, const ushort* __restrict__ wihl,
    const ushort* __restrict__ whhh, const ushort* __restrict__ whhl,
    const float* __restrict__ b_ih, const float* __restrict__ b_hh,
    float* __restrict__ hx, float* __restrict__ cx,
    ushort* __restrict__ nxh, ushort* __restrict__ nxl,
    float* __restrict__ hx_all_t)
{
    __shared__ float sg[2][64][16];   // 8 KB
    const int tid = threadIdx.x, bk = blockIdx.x;
    const int lane = tid & 63, wid = tid >> 6;
    const int mt = wid & 3, kh = wid >> 2;
    const int l15 = lane & 15, g = lane >> 4;
    const int arow = mt * 16 + l15;
    const int ncol = (l15 >> 2) * 1024 + bk * 4 + (l15 & 3);
    const int koff = g * 8;

    f32x4 acc0 = {}, acc1 = {};

    if (kh == 0) {
        {   // ctx . W_ih[:, 512:1024)  (16 kk)
            const ushort* ah = cth + (size_t)arow * 512 + koff;
            const ushort* al = ctl + (size_t)arow * 512 + koff;
            const ushort* bh = wihh + (size_t)ncol * 1024 + 512 + koff;
            const ushort* bl = wihl + (size_t)ncol * 1024 + 512 + koff;
            #pragma unroll 4
            for (int kk = 0; kk < 16; ++kk) {
                bfrag a_h = *(const bfrag*)(ah + kk * 32);
                bfrag a_l = *(const bfrag*)(al + kk * 32);
                bfrag b_h = *(const bfrag*)(bh + kk * 32);
                bfrag b_l = *(const bfrag*)(bl + kk * 32);
                acc0 = __builtin_amdgcn_mfma_f32_16x16x32_bf16(a_h, b_h, acc0, 0, 0, 0);
                acc1 = __builtin_amdgcn_mfma_f32_16x16x32_bf16(a_h, b_l, acc1, 0, 0, 0);
                acc1 = __builtin_amdgcn_mfma_f32_16x16x32_bf16(a_l, b_h, acc1, 0, 0, 0);
            }
        }
        {   // hx[0:256) . W_hh[:, 0:256)  (8 kk)
            const ushort* ah = hxh + (size_t)arow * 1024 + koff;
            const ushort* al = hxl + (size_t)arow * 1024 + koff;
            const ushort* bh = whhh + (size_t)ncol * 1024 + koff;
            const ushort* bl = whhl + (size_t)ncol * 1024 + koff;
            #pragma unroll 4
            for (int kk = 0; kk < 8; ++kk) {
                bfrag a_h = *(const bfrag*)(ah + kk * 32);
                bfrag a_l = *(const bfrag*)(al + kk * 32);
                bfrag b_h = *(const bfrag*)(bh + kk * 32);
                bfrag b_l = *(const bfrag*)(bl + kk * 32);
                acc0 = __builtin_amdgcn_mfma_f32_16x16x32_bf16(a_h, b_h, acc0, 0, 0, 0);
                acc1 = __builtin_amdgcn_mfma_f32_16x16x32_bf16(a_h, b_l, acc1, 0, 0, 0);
                acc1 = __builtin_amdgcn_mfma_f32_16x16x32_bf16(a_l, b_h, acc1, 0, 0, 0);
            }
        }
    } else {
        // hx[256:1024) . W_hh[:, 256:1024)  (24 kk)
        const ushort* ah = hxh + (size_t)arow * 1024 + 256 + koff;
        const ushort* al = hxl + (size_t)arow * 1024 + 256 + koff;
        const ushort* bh = whhh + (size_t)ncol * 1024 + 256 + koff;
        const ushort* bl = whhl + (size_t)ncol * 1024 + 256 + koff;
        #pragma unroll 4
        for (int kk = 0; kk < 24; ++kk) {
            bfrag a_h = *(const bfrag*)(ah + kk * 32);
            bfrag a_l = *(const bfrag*)(al + kk * 32);
            bfrag b_h = *(const bfrag*)(bh + kk * 32);
            bfrag b_l = *(const bfrag*)(bl + kk * 32);
            acc0 = __builtin_amdgcn_mfma_f32_16x16x32_bf16(a_h, b_h, acc0, 0, 0, 0);
            acc1 = __builtin_amdgcn_mfma_f32_16x16x32_bf16(a_h, b_l, acc1, 0, 0, 0);
            acc1 = __builtin_amdgcn_mfma_f32_16x16x32_bf16(a_l, b_h, acc1, 0, 0, 0);
        }
    }

    #pragma unroll
    for (int rr = 0; rr < 4; ++rr)
        sg[kh][mt * 16 + g * 4 + rr][l15] = acc0[rr] + acc1[rr];
    __syncthreads();

    if (tid < 256) {
        int b = tid >> 2, uu = tid & 3;
        int u = bk * 4 + uu;
        const float* gx = gxs_t + (size_t)b * 4096;
        float gi = sg[0][b][uu]      + sg[1][b][uu]      + gx[u]        + b_ih[u]        + b_hh[u];
        float gf = sg[0][b][4 + uu]  + sg[1][b][4 + uu]  + gx[1024 + u] + b_ih[1024 + u] + b_hh[1024 + u];
        float gg = sg[0][b][8 + uu]  + sg[1][b][8 + uu]  + gx[2048 + u] + b_ih[2048 + u] + b_hh[2048 + u];
        float go = sg[0][b][12 + uu] + sg[1][b][12 + uu] + gx[3072 + u] + b_ih[3072 + u] + b_hh[3072 + u];
        int idx = b * 1024 + u;
        float c = sigmoid_fast(gf) * cx[idx] + sigmoid_fast(gi) * tanh_fast(gg);
        float h = sigmoid_fast(go) * tanh_fast(c);
        cx[idx] = c;
        hx[idx] = h;
        hx_all_t[idx] = h;
        ushort hh = f2bf_rne(h);
        nxh[idx] = hh;
        nxl[idx] = f2bf_rne(h - bf2f(hh));
    }
}

// ---------------------------------------------------------------------------
extern "C" void kernel_launch(void* const* d_in, const int* in_sizes, int n_in,
                              void* d_out, int out_size, void* d_ws, size_t ws_size,
                              hipStream_t stream) {
    const float* features = (const float*)d_in[0];
    const int*   captions = (const int*)d_in[1];
    const float* E      = (const float*)d_in[3];
    const float* W_feat = (const float*)d_in[4];
    const float* b_feat = (const float*)d_in[5];
    const float* W1     = (const float*)d_in[6];
    const float* b1     = (const float*)d_in[7];
    const float* W2     = (const float*)d_in[8];
    const float* b2     = (const float*)d_in[9];
    const float* V      = (const float*)d_in[10];
    // d_in[11] bV: softmax-invariant, unused
    const float* W_hi   = (const float*)d_in[12];
    const float* b_hi   = (const float*)d_in[13];
    const float* W_ci   = (const float*)d_in[14];
    const float* b_ci   = (const float*)d_in[15];
    const float* W_ih   = (const float*)d_in[16];
    const float* b_ih   = (const float*)d_in[17];
    const float* W_hh   = (const float*)d_in[18];
    const float* b_hh   = (const float*)d_in[19];
    const float* W_out  = (const float*)d_in[20];
    const float* b_out  = (const float*)d_in[21];
    float* out = (float*)d_out;

    // ---- workspace layout ----
    float* ws = (float*)d_ws;
    float* f_buf   = ws;                          // 6,422,528
    float* fa_buf  = f_buf + 6422528;             // 6,422,528
    float* fmean   = fa_buf + 6422528;            // 32,768
    float* hx      = fmean + 32768;               // 65,536
    float* cx      = hx + 65536;                  // 65,536
    float* hx_all  = cx + 65536;                  // 1,310,720
    float* ha      = hx_all + 1310720;            // 32,768
    float* xs_f    = ha + 32768;                  // 622,592
    float* gxs     = xs_f + 622592;               // 4,980,736
    ushort* p = (ushort*)(gxs + 4980736);
    ushort* wfeat_hi = p;            p += 1048576;
    ushort* wfeat_lo = p;            p += 1048576;
    ushort* w1_hi    = p;            p += 262144;
    ushort* w1_lo    = p;            p += 262144;
    ushort* wih_hi   = p;            p += 4194304;
    ushort* wih_lo   = p;            p += 4194304;
    ushort* whh_hi   = p;            p += 4194304;
    ushort* whh_lo   = p;            p += 4194304;
    ushort* ctx_hi   = p;            p += 32768;
    ushort* ctx_lo   = p;            p += 32768;
    ushort* hxp      = p;            p += 262144;   // [2 bufs][hi|lo][65536]
    // W_out planes reuse f_buf+fa_buf region after the step loop (41MB <= 51MB)
    ushort* wout_hi = (ushort*)f_buf;
    ushort* wout_lo = wout_hi + 10240000;

    // ---- precompute ----
    k_split<<<1048576 / 4 / 256, 256, 0, stream>>>(W_feat, wfeat_hi, wfeat_lo, 1048576);
    k_split<<<262144 / 4 / 256, 256, 0, stream>>>(W1, w1_hi, w1_lo, 262144);
    k_split<<<4194304 / 4 / 256, 256, 0, stream>>>(W_ih, wih_hi, wih_lo, 4194304);
    k_split<<<4194304 / 4 / 256, 256, 0, stream>>>(W_hh, whh_hi, whh_lo, 4194304);
    k_embed<<<STEPS * BB, 128, 0, stream>>>(captions, E, xs_f);
    // f = features @ W_feat^T + b_feat  [12544,512], K=2048 (GLDS: B L2-hot)
    mfma_g<true, true><<<784, 256, 0, stream>>>(
        features, wfeat_hi, wfeat_lo, b_feat, f_buf, 512, 2048, 2048, 512, 4, 196);
    // fa = f @ W1^T + b1  [12544,512], K=512 (reg-staged B)
    mfma_g<true, false><<<784, 256, 0, stream>>>(
        f_buf, w1_hi, w1_lo, b1, fa_buf, 512, 512, 512, 512, 4, 196);
    // gxs = xs_flat @ W_ih[:, 0:512]^T  [1216,4096], K=512, Bld=1024
    mfma_g<false, false><<<608, 256, 0, stream>>>(
        xs_f, wih_hi, wih_lo, nullptr, gxs, 4096, 512, 1024, 4096, 32, 19);
    k_fmean2<<<256, 256, 0, stream>>>(f_buf, fmean);
    k_init2<<<512, 256, 0, stream>>>(fmean, W_hi, b_hi, W_ci, b_ci,
                                     hx, cx, hxp, hxp + 65536);

    // ---- recurrent steps: 3 dispatches per step ----
    for (int t = 0; t < STEPS; ++t) {
        ushort* hx_rd = hxp + (size_t)(t & 1) * 131072;
        ushort* hx_wr = hxp + (size_t)((t + 1) & 1) * 131072;
        k_ha<<<256, 256, 0, stream>>>(hx, W2, b2, ha);
        k_att<<<BB, 1024, 0, stream>>>(f_buf, fa_buf, ha, V, ctx_hi, ctx_lo);
        k_gates_lstm<<<256, 512, 0, stream>>>(
            gxs + (size_t)t * BB * 4096,
            ctx_hi, ctx_lo, hx_rd, hx_rd + 65536,
            wih_hi, wih_lo, whh_hi, whh_lo, b_ih, b_hh,
            hx, cx, hx_wr, hx_wr + 65536,
            hx_all + (size_t)t * BB * HID);
    }

    // ---- vocab projection over all steps: [1216,10000], K=1024 ----
    k_split<<<10240000 / 4 / 256, 256, 0, stream>>>(W_out, wout_hi, wout_lo, 10240000);
    mfma_g<false, false><<<1501, 256, 0, stream>>>(
        hx_all, wout_hi, wout_lo, b_out, out, VOCAB, HID, 1024, VOCAB, 79, 19);
}